// Round 4
// baseline (30873.392 us; speedup 1.0000x reference)
//
// TrajectoryPredictor: 2-layer GRU enc (50 steps) -> autoregressive 2-layer GRU dec (30 steps) + fc head.
// Strategy: fp16 MFMA (16x16x32_f16) GEMM per layer-step with gate math fused in epilogue.
// Hidden state stored fp16 ONLY (ping-pong), gate math in fp32.
// R2: XOR-swizzle LDS granules -> SQ_LDS_BANK_CONFLICT 4.4e7 -> 0.
// R3: (a) XCD-aware block swizzle: 8 col-blocks of one row-block -> same XCD, adjacent in dispatch
//         order => A-tile L2-resident, FETCH ~278->~90MB, staging drain ~900->~250cyc.
//     (b) __launch_bounds__(256,4): 4 blocks/CU (LDS 4x40KB=160KB, VGPR<=128) for latency hiding.
// ws usage ~147 MB: 4x fp16 state ping-pong (128MB) + packed weights (~18MB) + biases.
#include <hip/hip_runtime.h>
#include <hip/hip_fp16.h>
#include <stdint.h>

typedef _Float16 h8 __attribute__((ext_vector_type(8)));
typedef float f4 __attribute__((ext_vector_type(4)));

#define DEV static __device__ __forceinline__

constexpr int BATCH  = 32768;
constexpr int HID    = 512;
constexpr int T_HIST = 50;
constexpr int FUT    = 30;
constexpr int BM = 128, BN = 64, BK = 64;

DEV void gl2lds16(const void* g, void* l) {
  __builtin_amdgcn_global_load_lds(
      (const __attribute__((address_space(1))) void*)g,
      (__attribute__((address_space(3))) void*)l,
      16, 0, 0);
}

DEV float sigm(float x)     { return 1.f / (1.f + __expf(-x)); }
DEV float tanhfast(float x) { return 1.f - 2.f / (__expf(2.f * x) + 1.f); }

// ---------------- utility: zero fill (graph-safe) ----------------
__global__ void zero_fill(float4* __restrict__ p, int n4) {
  int i = blockIdx.x * 256 + threadIdx.x;
  if (i < n4) p[i] = float4{0.f, 0.f, 0.f, 0.f};
}

// ---------------- weight/bias repack kernels ----------------

// target layout: (((nb*KC + kc)*3 + g)*64 + n)*64 + k, with 16B-granule XOR swizzle:
// stored granule k8s holds logical granule k8 = k8s ^ (n&7). source row = g*512 + nb*64 + n.
__global__ void pack_w(const float* __restrict__ Wa, const float* __restrict__ Wb,
                       _Float16* __restrict__ out, int KC) {
  int i = blockIdx.x * 256 + threadIdx.x;
  int total = 8 * KC * 3 * 64 * 64;
  if (i >= total) return;
  int k0  = i & 7;          // element within 16B granule
  int k8s = (i >> 3) & 7;   // stored granule index
  int n   = (i >> 6) & 63;
  int t   = i >> 12;        // (nb*KC + kc)*3 + g
  int g   = t % 3;
  int t2  = t / 3;
  int kc  = t2 % KC;
  int nb  = t2 / KC;
  int k8  = k8s ^ (n & 7);  // logical granule
  int row = g * 512 + nb * 64 + n;
  int kg  = kc * 64 + k8 * 8 + k0;
  float v = (kg < 512) ? Wa[(size_t)row * 512 + kg] : Wb[(size_t)row * 512 + kg - 512];
  out[i] = (_Float16)v;
}

// bias combine: [0]=b_ih_r+b_hh_r, [1]=b_ih_z+b_hh_z, [2]=b_ih_n, [3]=b_hh_n  (each 512)
__global__ void pack_bias(const float* __restrict__ bih, const float* __restrict__ bhh,
                          float* __restrict__ out) {
  int j = blockIdx.x * 256 + threadIdx.x;
  if (j >= 512) return;
  out[j]        = bih[j]        + bhh[j];
  out[512 + j]  = bih[512 + j]  + bhh[512 + j];
  out[1024 + j] = bih[1024 + j];
  out[1536 + j] = bhh[1024 + j];
}

// x-weights for layer0 (K=3): out[j*9 + g*3 + k] = W_ih[(g*512+j)*3 + k]
__global__ void pack_wx(const float* __restrict__ Wih, float* __restrict__ out) {
  int i = blockIdx.x * 256 + threadIdx.x;
  if (i >= 512 * 9) return;
  int j = i / 9, q = i % 9, g = q / 3, k = q % 3;
  out[i] = Wih[(size_t)(g * 512 + j) * 3 + k];
}

// ---------------- fused GRU layer-step GEMM ----------------
// KC = Ktot/64 (8 for layer0, 16 for layer1). L0: x-part (K=3) handled in epilogue via Wx.
// grid: flat 2048 blocks; XCD-aware remap inside kernel (see header comment).
template <int KC, bool L0>
__launch_bounds__(256, 4)
__global__ void gru_step(const _Float16* __restrict__ Bp,     // packed weights [8][KC][3][64][64] (swizzled)
                         const _Float16* __restrict__ Alo,    // fp16 A, k<512 (L0: old state; L1: layer0 out)
                         const _Float16* __restrict__ Ahi,    // fp16 A, k>=512 (L1: old state)
                         _Float16* __restrict__ hnew16,       // fp16 new state
                         const float* __restrict__ bias,      // [4*512]
                         const float* __restrict__ Wx,        // [512*9] (L0) or null
                         const float* __restrict__ xin,       // x row base (L0) or null
                         int xstride) {
  __shared__ alignas(16) _Float16 sA[BM * BK];        // [m][k] 16KB, granule-swizzled
  __shared__ alignas(16) _Float16 sB[3 * BN * BK];    // [g][n][k] 24KB, granule-swizzled

  const int tid  = threadIdx.x;
  const int wave = tid >> 6;
  const int lane = tid & 63;
  const int quad = lane >> 4;
  const int l15  = lane & 15;
  // XCD-aware swizzle: XCD = L mod 8 (round-robin heuristic). The 8 col-blocks of one
  // row-block get L = c + 8*(rbh*8 + cb): same XCD c, spaced 8 apart (temporally adjacent).
  const int L  = blockIdx.x;
  const int c  = L & 7;
  const int q  = L >> 3;          // 0..255
  const int cb = q & 7;
  const int rb = c * 32 + (q >> 3);
  const int row0 = rb * BM;
  const int col0 = cb * BN;

  f4 acc_r[2][4]  = {};
  f4 acc_z[2][4]  = {};
  f4 acc_n0[2][4] = {};   // L1: i_n (kc<8); L0 unused
  f4 acc_n1[2][4] = {};   // h_n

  const _Float16* Bblk = Bp + (size_t)cb * KC * (3 * BN * BK);

  for (int kc = 0; kc < KC; ++kc) {
    const _Float16* Asrc = (KC == 16 && kc >= 8) ? Ahi : Alo;
    const int kb = (kc & 7) * BK;
    // stage A: 128x64 fp16, 4 issues/wave. LDS slot (m, k8s) holds logical granule k8s^(m&7):
    // lane's LDS dest is fixed (base + lane*16), so fetch the permuted granule from global.
#pragma unroll
    for (int i = 0; i < 4; ++i) {
      int ga = wave * 256 + i * 64 + lane;     // 16B slot index = m*8 + k8s
      int m = ga >> 3, k8s = ga & 7;
      int k8l = k8s ^ (m & 7);                 // logical granule to fetch
      gl2lds16(Asrc + (size_t)(row0 + m) * HID + kb + k8l * 8,
               &sA[(wave * 256 + i * 64) * 8]);
    }
    // stage B: 24KB linear copy (swizzle pre-baked by pack_w), 6 issues/wave
    const _Float16* Bsrc = Bblk + (size_t)kc * (3 * BN * BK);
#pragma unroll
    for (int i = 0; i < 6; ++i) {
      int gb = wave * 384 + i * 64 + lane;
      gl2lds16(Bsrc + (size_t)gb * 8, &sB[(wave * 384 + i * 64) * 8]);
    }
    __syncthreads();   // drains vmcnt then barriers
#pragma unroll
    for (int s = 0; s < 2; ++s) {
      // swizzled granule offset (in halfs) for this lane: rows ≡ l15 (mod 8) for both A and B reads
      const int sw = ((s * 4 + quad) ^ (l15 & 7)) * 8;
      h8 af[2];
#pragma unroll
      for (int mt = 0; mt < 2; ++mt)
        af[mt] = *(const h8*)&sA[(wave * 32 + mt * 16 + l15) * BK + sw];
#pragma unroll
      for (int nt = 0; nt < 4; ++nt) {
        const int nrow = nt * 16 + l15;
        h8 br = *(const h8*)&sB[(0 * BN + nrow) * BK + sw];
        h8 bz = *(const h8*)&sB[(1 * BN + nrow) * BK + sw];
        h8 bn = *(const h8*)&sB[(2 * BN + nrow) * BK + sw];
#pragma unroll
        for (int mt = 0; mt < 2; ++mt) {
          acc_r[mt][nt] = __builtin_amdgcn_mfma_f32_16x16x32_f16(af[mt], br, acc_r[mt][nt], 0, 0, 0);
          acc_z[mt][nt] = __builtin_amdgcn_mfma_f32_16x16x32_f16(af[mt], bz, acc_z[mt][nt], 0, 0, 0);
          if (L0 || kc >= 8)
            acc_n1[mt][nt] = __builtin_amdgcn_mfma_f32_16x16x32_f16(af[mt], bn, acc_n1[mt][nt], 0, 0, 0);
          else
            acc_n0[mt][nt] = __builtin_amdgcn_mfma_f32_16x16x32_f16(af[mt], bn, acc_n0[mt][nt], 0, 0, 0);
        }
      }
    }
    __syncthreads();
  }

  // ---------------- fused epilogue: gates + state update ----------------
  const _Float16* hold16 = L0 ? Alo : Ahi;
  float bR[4], bZ[4], bI[4], bH[4];
  float wx[4][9];
#pragma unroll
  for (int nt = 0; nt < 4; ++nt) {
    int j = col0 + nt * 16 + l15;
    bR[nt] = bias[j];
    bZ[nt] = bias[512 + j];
    bI[nt] = bias[1024 + j];
    bH[nt] = bias[1536 + j];
    if constexpr (L0) {
#pragma unroll
      for (int q2 = 0; q2 < 9; ++q2) wx[nt][q2] = Wx[j * 9 + q2];
    }
  }
  float xv[2][4][3];
  if constexpr (L0) {
#pragma unroll
    for (int mt = 0; mt < 2; ++mt)
#pragma unroll
      for (int r = 0; r < 4; ++r) {
        int b = row0 + wave * 32 + mt * 16 + quad * 4 + r;
        const float* xp = xin + (size_t)b * xstride;
        xv[mt][r][0] = xp[0]; xv[mt][r][1] = xp[1]; xv[mt][r][2] = xp[2];
      }
  }
#pragma unroll
  for (int mt = 0; mt < 2; ++mt) {
#pragma unroll
    for (int r = 0; r < 4; ++r) {
      int b = row0 + wave * 32 + mt * 16 + quad * 4 + r;   // C/D: row = quad*4+reg
#pragma unroll
      for (int nt = 0; nt < 4; ++nt) {
        int j = col0 + nt * 16 + l15;                       // C/D: col = lane&15
        size_t idx = (size_t)b * HID + j;
        float rr = acc_r[mt][nt][r] + bR[nt];
        float zz = acc_z[mt][nt][r] + bZ[nt];
        float hn = acc_n1[mt][nt][r] + bH[nt];
        float in_;
        if constexpr (L0) {
          const float* w = wx[nt];
          rr += xv[mt][r][0] * w[0] + xv[mt][r][1] * w[1] + xv[mt][r][2] * w[2];
          zz += xv[mt][r][0] * w[3] + xv[mt][r][1] * w[4] + xv[mt][r][2] * w[5];
          in_ = bI[nt] + xv[mt][r][0] * w[6] + xv[mt][r][1] * w[7] + xv[mt][r][2] * w[8];
        } else {
          in_ = acc_n0[mt][nt][r] + bI[nt];
        }
        float rg = sigm(rr);
        float zg = sigm(zz);
        float ng = tanhfast(in_ + rg * hn);
        float hp = (float)hold16[idx];
        float hv = (1.f - zg) * ng + zg * hp;
        hnew16[idx] = (_Float16)hv;
      }
    }
  }
}

// ---------------- fc head: pred[b,d] = h[b,:] . fcW[d,:] + fcb[d] ----------------
__global__ __launch_bounds__(256) void fc_kernel(const _Float16* __restrict__ h,
                                                 const float* __restrict__ W,
                                                 const float* __restrict__ bfc,
                                                 float* __restrict__ out) {  // out = d_out + t*3
  int wave = threadIdx.x >> 6, lane = threadIdx.x & 63;
  int b = blockIdx.x * 4 + wave;
  const h8* hp = (const h8*)(h + (size_t)b * 512);
  h8 a0 = hp[lane];   // 8 contiguous fp16 per lane
  float s[3];
#pragma unroll
  for (int d = 0; d < 3; ++d) {
    const float4* wp = (const float4*)(W + d * 512);
    float4 w0 = wp[lane * 2], w1 = wp[lane * 2 + 1];
    s[d] = (float)a0[0] * w0.x + (float)a0[1] * w0.y + (float)a0[2] * w0.z + (float)a0[3] * w0.w
         + (float)a0[4] * w1.x + (float)a0[5] * w1.y + (float)a0[6] * w1.z + (float)a0[7] * w1.w;
  }
#pragma unroll
  for (int d = 0; d < 3; ++d)
#pragma unroll
    for (int off = 32; off > 0; off >>= 1) s[d] += __shfl_xor(s[d], off, 64);
  if (lane == 0) {
    out[(size_t)b * 90 + 0] = s[0] + bfc[0];
    out[(size_t)b * 90 + 1] = s[1] + bfc[1];
    out[(size_t)b * 90 + 2] = s[2] + bfc[2];
  }
}

extern "C" void kernel_launch(void* const* d_in, const int* in_sizes, int n_in,
                              void* d_out, int out_size, void* d_ws, size_t ws_size,
                              hipStream_t stream) {
  (void)in_sizes; (void)n_in; (void)out_size; (void)ws_size;
  const float* x_input = (const float*)d_in[0];
  const float* eWih0 = (const float*)d_in[2];
  const float* eWhh0 = (const float*)d_in[3];
  const float* ebih0 = (const float*)d_in[4];
  const float* ebhh0 = (const float*)d_in[5];
  const float* eWih1 = (const float*)d_in[6];
  const float* eWhh1 = (const float*)d_in[7];
  const float* ebih1 = (const float*)d_in[8];
  const float* ebhh1 = (const float*)d_in[9];
  const float* dWih0 = (const float*)d_in[10];
  const float* dWhh0 = (const float*)d_in[11];
  const float* dbih0 = (const float*)d_in[12];
  const float* dbhh0 = (const float*)d_in[13];
  const float* dWih1 = (const float*)d_in[14];
  const float* dWhh1 = (const float*)d_in[15];
  const float* dbih1 = (const float*)d_in[16];
  const float* dbhh1 = (const float*)d_in[17];
  const float* fcW   = (const float*)d_in[18];
  const float* fcb   = (const float*)d_in[19];
  float* out = (float*)d_out;

  char* ws = (char*)d_ws;
  const size_t S16 = (size_t)BATCH * HID * 2;   // 32MB
  _Float16* h0h[2] = {(_Float16*)(ws),            (_Float16*)(ws + S16)};
  _Float16* h1h[2] = {(_Float16*)(ws + 2 * S16),  (_Float16*)(ws + 3 * S16)};
  char* p = ws + 4 * S16;                        // 128MB
  _Float16* pkE0 = (_Float16*)p; p += (size_t)8 * 8  * 3 * 64 * 64 * 2;  // 3MB
  _Float16* pkE1 = (_Float16*)p; p += (size_t)8 * 16 * 3 * 64 * 64 * 2;  // 6MB
  _Float16* pkD0 = (_Float16*)p; p += (size_t)8 * 8  * 3 * 64 * 64 * 2;  // 3MB
  _Float16* pkD1 = (_Float16*)p; p += (size_t)8 * 16 * 3 * 64 * 64 * 2;  // 6MB
  float* bE0 = (float*)p; p += 2048 * 4;
  float* bE1 = (float*)p; p += 2048 * 4;
  float* bD0 = (float*)p; p += 2048 * 4;
  float* bD1 = (float*)p; p += 2048 * 4;
  float* wxE = (float*)p; p += 512 * 9 * 4;
  float* wxD = (float*)p; p += 512 * 9 * 4;
  // total ws usage: 128MB + ~18.1MB

  // repack weights/biases (every call; ws is re-poisoned by harness)
  pack_w<<<dim3((8 * 8  * 3 * 64 * 64) / 256), 256, 0, stream>>>(eWhh0, eWhh0, pkE0, 8);
  pack_w<<<dim3((8 * 16 * 3 * 64 * 64) / 256), 256, 0, stream>>>(eWih1, eWhh1, pkE1, 16);
  pack_w<<<dim3((8 * 8  * 3 * 64 * 64) / 256), 256, 0, stream>>>(dWhh0, dWhh0, pkD0, 8);
  pack_w<<<dim3((8 * 16 * 3 * 64 * 64) / 256), 256, 0, stream>>>(dWih1, dWhh1, pkD1, 16);
  pack_bias<<<2, 256, 0, stream>>>(ebih0, ebhh0, bE0);
  pack_bias<<<2, 256, 0, stream>>>(ebih1, ebhh1, bE1);
  pack_bias<<<2, 256, 0, stream>>>(dbih0, dbhh0, bD0);
  pack_bias<<<2, 256, 0, stream>>>(dbih1, dbhh1, bD1);
  pack_wx<<<18, 256, 0, stream>>>(eWih0, wxE);
  pack_wx<<<18, 256, 0, stream>>>(dWih0, wxD);

  // zero-init fp16 states (ping index 0)
  {
    int n4 = (int)(S16 / 16);
    zero_fill<<<(n4 + 255) / 256, 256, 0, stream>>>((float4*)h0h[0], n4);
    zero_fill<<<(n4 + 255) / 256, 256, 0, stream>>>((float4*)h1h[0], n4);
  }

  dim3 grid(2048), blk(256);
  int p0 = 0, p1 = 0;
  // encoder
  for (int t = 0; t < T_HIST; ++t) {
    gru_step<8, true><<<grid, blk, 0, stream>>>(pkE0, h0h[p0], nullptr,
                                                h0h[1 - p0], bE0, wxE,
                                                x_input + (size_t)t * 3, 150);
    p0 ^= 1;
    gru_step<16, false><<<grid, blk, 0, stream>>>(pkE1, h0h[p0], h1h[p1],
                                                  h1h[1 - p1], bE1, nullptr, nullptr, 0);
    p1 ^= 1;
  }
  // autoregressive decoder
  for (int t = 0; t < FUT; ++t) {
    const float* xp; int xs;
    if (t == 0) { xp = x_input + (size_t)49 * 3; xs = 150; }
    else        { xp = out + (size_t)(t - 1) * 3; xs = 90; }
    gru_step<8, true><<<grid, blk, 0, stream>>>(pkD0, h0h[p0], nullptr,
                                                h0h[1 - p0], bD0, wxD, xp, xs);
    p0 ^= 1;
    gru_step<16, false><<<grid, blk, 0, stream>>>(pkD1, h0h[p0], h1h[p1],
                                                  h1h[1 - p1], bD1, nullptr, nullptr, 0);
    p1 ^= 1;
    fc_kernel<<<8192, 256, 0, stream>>>(h1h[p1], fcW, fcb, out + (size_t)t * 3);
  }
}

// Round 5
// 17140.613 us; speedup vs baseline: 1.8012x; 1.8012x over previous
//
// TrajectoryPredictor: 2-layer GRU enc (50 steps) -> autoregressive 2-layer GRU dec (30 steps) + fc head.
// Strategy: fp16 MFMA (16x16x32_f16) GEMM per layer-step with gate math fused in epilogue.
// Hidden state stored fp16 ONLY (ping-pong), gate math in fp32.
// R2: XOR-swizzle LDS granules -> SQ_LDS_BANK_CONFLICT 4.4e7 -> 0.
// R3: XCD-aware block swizzle (A-tile L2 locality).
// R4 FAILED: launch_bounds(256,4) -> 128-reg cap < 160 needed (96 arch + 64 acc unified) ->
//            accumulator spill, WRITE_SIZE 32->352MB, 2x slower. Lesson: unified VGPR+AGPR budget.
// R5: launch_bounds(256,3) -> 170-reg cap >= 160, 3 blocks/CU (LDS 120/160KB), no spill.
// ws usage ~147 MB: 4x fp16 state ping-pong (128MB) + packed weights (~18MB) + biases.
#include <hip/hip_runtime.h>
#include <hip/hip_fp16.h>
#include <stdint.h>

typedef _Float16 h8 __attribute__((ext_vector_type(8)));
typedef float f4 __attribute__((ext_vector_type(4)));

#define DEV static __device__ __forceinline__

constexpr int BATCH  = 32768;
constexpr int HID    = 512;
constexpr int T_HIST = 50;
constexpr int FUT    = 30;
constexpr int BM = 128, BN = 64, BK = 64;

DEV void gl2lds16(const void* g, void* l) {
  __builtin_amdgcn_global_load_lds(
      (const __attribute__((address_space(1))) void*)g,
      (__attribute__((address_space(3))) void*)l,
      16, 0, 0);
}

DEV float sigm(float x)     { return 1.f / (1.f + __expf(-x)); }
DEV float tanhfast(float x) { return 1.f - 2.f / (__expf(2.f * x) + 1.f); }

// ---------------- utility: zero fill (graph-safe) ----------------
__global__ void zero_fill(float4* __restrict__ p, int n4) {
  int i = blockIdx.x * 256 + threadIdx.x;
  if (i < n4) p[i] = float4{0.f, 0.f, 0.f, 0.f};
}

// ---------------- weight/bias repack kernels ----------------

// target layout: (((nb*KC + kc)*3 + g)*64 + n)*64 + k, with 16B-granule XOR swizzle:
// stored granule k8s holds logical granule k8 = k8s ^ (n&7). source row = g*512 + nb*64 + n.
__global__ void pack_w(const float* __restrict__ Wa, const float* __restrict__ Wb,
                       _Float16* __restrict__ out, int KC) {
  int i = blockIdx.x * 256 + threadIdx.x;
  int total = 8 * KC * 3 * 64 * 64;
  if (i >= total) return;
  int k0  = i & 7;          // element within 16B granule
  int k8s = (i >> 3) & 7;   // stored granule index
  int n   = (i >> 6) & 63;
  int t   = i >> 12;        // (nb*KC + kc)*3 + g
  int g   = t % 3;
  int t2  = t / 3;
  int kc  = t2 % KC;
  int nb  = t2 / KC;
  int k8  = k8s ^ (n & 7);  // logical granule
  int row = g * 512 + nb * 64 + n;
  int kg  = kc * 64 + k8 * 8 + k0;
  float v = (kg < 512) ? Wa[(size_t)row * 512 + kg] : Wb[(size_t)row * 512 + kg - 512];
  out[i] = (_Float16)v;
}

// bias combine: [0]=b_ih_r+b_hh_r, [1]=b_ih_z+b_hh_z, [2]=b_ih_n, [3]=b_hh_n  (each 512)
__global__ void pack_bias(const float* __restrict__ bih, const float* __restrict__ bhh,
                          float* __restrict__ out) {
  int j = blockIdx.x * 256 + threadIdx.x;
  if (j >= 512) return;
  out[j]        = bih[j]        + bhh[j];
  out[512 + j]  = bih[512 + j]  + bhh[512 + j];
  out[1024 + j] = bih[1024 + j];
  out[1536 + j] = bhh[1024 + j];
}

// x-weights for layer0 (K=3): out[j*9 + g*3 + k] = W_ih[(g*512+j)*3 + k]
__global__ void pack_wx(const float* __restrict__ Wih, float* __restrict__ out) {
  int i = blockIdx.x * 256 + threadIdx.x;
  if (i >= 512 * 9) return;
  int j = i / 9, q = i % 9, g = q / 3, k = q % 3;
  out[i] = Wih[(size_t)(g * 512 + j) * 3 + k];
}

// ---------------- fused GRU layer-step GEMM ----------------
// KC = Ktot/64 (8 for layer0, 16 for layer1). L0: x-part (K=3) handled in epilogue via Wx.
// grid: flat 2048 blocks; XCD-aware remap inside kernel.
template <int KC, bool L0>
__launch_bounds__(256, 3)
__global__ void gru_step(const _Float16* __restrict__ Bp,     // packed weights [8][KC][3][64][64] (swizzled)
                         const _Float16* __restrict__ Alo,    // fp16 A, k<512 (L0: old state; L1: layer0 out)
                         const _Float16* __restrict__ Ahi,    // fp16 A, k>=512 (L1: old state)
                         _Float16* __restrict__ hnew16,       // fp16 new state
                         const float* __restrict__ bias,      // [4*512]
                         const float* __restrict__ Wx,        // [512*9] (L0) or null
                         const float* __restrict__ xin,       // x row base (L0) or null
                         int xstride) {
  __shared__ alignas(16) _Float16 sA[BM * BK];        // [m][k] 16KB, granule-swizzled
  __shared__ alignas(16) _Float16 sB[3 * BN * BK];    // [g][n][k] 24KB, granule-swizzled

  const int tid  = threadIdx.x;
  const int wave = tid >> 6;
  const int lane = tid & 63;
  const int quad = lane >> 4;
  const int l15  = lane & 15;
  // XCD-aware swizzle: XCD = L mod 8 (round-robin heuristic). The 8 col-blocks of one
  // row-block get L = c + 8*(rbh*8 + cb): same XCD c, spaced 8 apart (temporally adjacent).
  const int L  = blockIdx.x;
  const int c  = L & 7;
  const int q  = L >> 3;          // 0..255
  const int cb = q & 7;
  const int rb = c * 32 + (q >> 3);
  const int row0 = rb * BM;
  const int col0 = cb * BN;

  f4 acc_r[2][4]  = {};
  f4 acc_z[2][4]  = {};
  f4 acc_n0[2][4] = {};   // L1: i_n (kc<8); L0 unused
  f4 acc_n1[2][4] = {};   // h_n

  const _Float16* Bblk = Bp + (size_t)cb * KC * (3 * BN * BK);

  for (int kc = 0; kc < KC; ++kc) {
    const _Float16* Asrc = (KC == 16 && kc >= 8) ? Ahi : Alo;
    const int kb = (kc & 7) * BK;
    // stage A: 128x64 fp16, 4 issues/wave. LDS slot (m, k8s) holds logical granule k8s^(m&7):
    // lane's LDS dest is fixed (base + lane*16), so fetch the permuted granule from global.
#pragma unroll
    for (int i = 0; i < 4; ++i) {
      int ga = wave * 256 + i * 64 + lane;     // 16B slot index = m*8 + k8s
      int m = ga >> 3, k8s = ga & 7;
      int k8l = k8s ^ (m & 7);                 // logical granule to fetch
      gl2lds16(Asrc + (size_t)(row0 + m) * HID + kb + k8l * 8,
               &sA[(wave * 256 + i * 64) * 8]);
    }
    // stage B: 24KB linear copy (swizzle pre-baked by pack_w), 6 issues/wave
    const _Float16* Bsrc = Bblk + (size_t)kc * (3 * BN * BK);
#pragma unroll
    for (int i = 0; i < 6; ++i) {
      int gb = wave * 384 + i * 64 + lane;
      gl2lds16(Bsrc + (size_t)gb * 8, &sB[(wave * 384 + i * 64) * 8]);
    }
    __syncthreads();   // drains vmcnt then barriers
#pragma unroll
    for (int s = 0; s < 2; ++s) {
      // swizzled granule offset (in halfs) for this lane: rows ≡ l15 (mod 8) for both A and B reads
      const int sw = ((s * 4 + quad) ^ (l15 & 7)) * 8;
      h8 af[2];
#pragma unroll
      for (int mt = 0; mt < 2; ++mt)
        af[mt] = *(const h8*)&sA[(wave * 32 + mt * 16 + l15) * BK + sw];
#pragma unroll
      for (int nt = 0; nt < 4; ++nt) {
        const int nrow = nt * 16 + l15;
        h8 br = *(const h8*)&sB[(0 * BN + nrow) * BK + sw];
        h8 bz = *(const h8*)&sB[(1 * BN + nrow) * BK + sw];
        h8 bn = *(const h8*)&sB[(2 * BN + nrow) * BK + sw];
#pragma unroll
        for (int mt = 0; mt < 2; ++mt) {
          acc_r[mt][nt] = __builtin_amdgcn_mfma_f32_16x16x32_f16(af[mt], br, acc_r[mt][nt], 0, 0, 0);
          acc_z[mt][nt] = __builtin_amdgcn_mfma_f32_16x16x32_f16(af[mt], bz, acc_z[mt][nt], 0, 0, 0);
          if (L0 || kc >= 8)
            acc_n1[mt][nt] = __builtin_amdgcn_mfma_f32_16x16x32_f16(af[mt], bn, acc_n1[mt][nt], 0, 0, 0);
          else
            acc_n0[mt][nt] = __builtin_amdgcn_mfma_f32_16x16x32_f16(af[mt], bn, acc_n0[mt][nt], 0, 0, 0);
        }
      }
    }
    __syncthreads();
  }

  // ---------------- fused epilogue: gates + state update ----------------
  const _Float16* hold16 = L0 ? Alo : Ahi;
  float bR[4], bZ[4], bI[4], bH[4];
  float wx[4][9];
#pragma unroll
  for (int nt = 0; nt < 4; ++nt) {
    int j = col0 + nt * 16 + l15;
    bR[nt] = bias[j];
    bZ[nt] = bias[512 + j];
    bI[nt] = bias[1024 + j];
    bH[nt] = bias[1536 + j];
    if constexpr (L0) {
#pragma unroll
      for (int q2 = 0; q2 < 9; ++q2) wx[nt][q2] = Wx[j * 9 + q2];
    }
  }
  float xv[2][4][3];
  if constexpr (L0) {
#pragma unroll
    for (int mt = 0; mt < 2; ++mt)
#pragma unroll
      for (int r = 0; r < 4; ++r) {
        int b = row0 + wave * 32 + mt * 16 + quad * 4 + r;
        const float* xp = xin + (size_t)b * xstride;
        xv[mt][r][0] = xp[0]; xv[mt][r][1] = xp[1]; xv[mt][r][2] = xp[2];
      }
  }
#pragma unroll
  for (int mt = 0; mt < 2; ++mt) {
#pragma unroll
    for (int r = 0; r < 4; ++r) {
      int b = row0 + wave * 32 + mt * 16 + quad * 4 + r;   // C/D: row = quad*4+reg
#pragma unroll
      for (int nt = 0; nt < 4; ++nt) {
        int j = col0 + nt * 16 + l15;                       // C/D: col = lane&15
        size_t idx = (size_t)b * HID + j;
        float rr = acc_r[mt][nt][r] + bR[nt];
        float zz = acc_z[mt][nt][r] + bZ[nt];
        float hn = acc_n1[mt][nt][r] + bH[nt];
        float in_;
        if constexpr (L0) {
          const float* w = wx[nt];
          rr += xv[mt][r][0] * w[0] + xv[mt][r][1] * w[1] + xv[mt][r][2] * w[2];
          zz += xv[mt][r][0] * w[3] + xv[mt][r][1] * w[4] + xv[mt][r][2] * w[5];
          in_ = bI[nt] + xv[mt][r][0] * w[6] + xv[mt][r][1] * w[7] + xv[mt][r][2] * w[8];
        } else {
          in_ = acc_n0[mt][nt][r] + bI[nt];
        }
        float rg = sigm(rr);
        float zg = sigm(zz);
        float ng = tanhfast(in_ + rg * hn);
        float hp = (float)hold16[idx];
        float hv = (1.f - zg) * ng + zg * hp;
        hnew16[idx] = (_Float16)hv;
      }
    }
  }
}

// ---------------- fc head: pred[b,d] = h[b,:] . fcW[d,:] + fcb[d] ----------------
__global__ __launch_bounds__(256) void fc_kernel(const _Float16* __restrict__ h,
                                                 const float* __restrict__ W,
                                                 const float* __restrict__ bfc,
                                                 float* __restrict__ out) {  // out = d_out + t*3
  int wave = threadIdx.x >> 6, lane = threadIdx.x & 63;
  int b = blockIdx.x * 4 + wave;
  const h8* hp = (const h8*)(h + (size_t)b * 512);
  h8 a0 = hp[lane];   // 8 contiguous fp16 per lane
  float s[3];
#pragma unroll
  for (int d = 0; d < 3; ++d) {
    const float4* wp = (const float4*)(W + d * 512);
    float4 w0 = wp[lane * 2], w1 = wp[lane * 2 + 1];
    s[d] = (float)a0[0] * w0.x + (float)a0[1] * w0.y + (float)a0[2] * w0.z + (float)a0[3] * w0.w
         + (float)a0[4] * w1.x + (float)a0[5] * w1.y + (float)a0[6] * w1.z + (float)a0[7] * w1.w;
  }
#pragma unroll
  for (int d = 0; d < 3; ++d)
#pragma unroll
    for (int off = 32; off > 0; off >>= 1) s[d] += __shfl_xor(s[d], off, 64);
  if (lane == 0) {
    out[(size_t)b * 90 + 0] = s[0] + bfc[0];
    out[(size_t)b * 90 + 1] = s[1] + bfc[1];
    out[(size_t)b * 90 + 2] = s[2] + bfc[2];
  }
}

extern "C" void kernel_launch(void* const* d_in, const int* in_sizes, int n_in,
                              void* d_out, int out_size, void* d_ws, size_t ws_size,
                              hipStream_t stream) {
  (void)in_sizes; (void)n_in; (void)out_size; (void)ws_size;
  const float* x_input = (const float*)d_in[0];
  const float* eWih0 = (const float*)d_in[2];
  const float* eWhh0 = (const float*)d_in[3];
  const float* ebih0 = (const float*)d_in[4];
  const float* ebhh0 = (const float*)d_in[5];
  const float* eWih1 = (const float*)d_in[6];
  const float* eWhh1 = (const float*)d_in[7];
  const float* ebih1 = (const float*)d_in[8];
  const float* ebhh1 = (const float*)d_in[9];
  const float* dWih0 = (const float*)d_in[10];
  const float* dWhh0 = (const float*)d_in[11];
  const float* dbih0 = (const float*)d_in[12];
  const float* dbhh0 = (const float*)d_in[13];
  const float* dWih1 = (const float*)d_in[14];
  const float* dWhh1 = (const float*)d_in[15];
  const float* dbih1 = (const float*)d_in[16];
  const float* dbhh1 = (const float*)d_in[17];
  const float* fcW   = (const float*)d_in[18];
  const float* fcb   = (const float*)d_in[19];
  float* out = (float*)d_out;

  char* ws = (char*)d_ws;
  const size_t S16 = (size_t)BATCH * HID * 2;   // 32MB
  _Float16* h0h[2] = {(_Float16*)(ws),            (_Float16*)(ws + S16)};
  _Float16* h1h[2] = {(_Float16*)(ws + 2 * S16),  (_Float16*)(ws + 3 * S16)};
  char* p = ws + 4 * S16;                        // 128MB
  _Float16* pkE0 = (_Float16*)p; p += (size_t)8 * 8  * 3 * 64 * 64 * 2;  // 3MB
  _Float16* pkE1 = (_Float16*)p; p += (size_t)8 * 16 * 3 * 64 * 64 * 2;  // 6MB
  _Float16* pkD0 = (_Float16*)p; p += (size_t)8 * 8  * 3 * 64 * 64 * 2;  // 3MB
  _Float16* pkD1 = (_Float16*)p; p += (size_t)8 * 16 * 3 * 64 * 64 * 2;  // 6MB
  float* bE0 = (float*)p; p += 2048 * 4;
  float* bE1 = (float*)p; p += 2048 * 4;
  float* bD0 = (float*)p; p += 2048 * 4;
  float* bD1 = (float*)p; p += 2048 * 4;
  float* wxE = (float*)p; p += 512 * 9 * 4;
  float* wxD = (float*)p; p += 512 * 9 * 4;
  // total ws usage: 128MB + ~18.1MB

  // repack weights/biases (every call; ws is re-poisoned by harness)
  pack_w<<<dim3((8 * 8  * 3 * 64 * 64) / 256), 256, 0, stream>>>(eWhh0, eWhh0, pkE0, 8);
  pack_w<<<dim3((8 * 16 * 3 * 64 * 64) / 256), 256, 0, stream>>>(eWih1, eWhh1, pkE1, 16);
  pack_w<<<dim3((8 * 8  * 3 * 64 * 64) / 256), 256, 0, stream>>>(dWhh0, dWhh0, pkD0, 8);
  pack_w<<<dim3((8 * 16 * 3 * 64 * 64) / 256), 256, 0, stream>>>(dWih1, dWhh1, pkD1, 16);
  pack_bias<<<2, 256, 0, stream>>>(ebih0, ebhh0, bE0);
  pack_bias<<<2, 256, 0, stream>>>(ebih1, ebhh1, bE1);
  pack_bias<<<2, 256, 0, stream>>>(dbih0, dbhh0, bD0);
  pack_bias<<<2, 256, 0, stream>>>(dbih1, dbhh1, bD1);
  pack_wx<<<18, 256, 0, stream>>>(eWih0, wxE);
  pack_wx<<<18, 256, 0, stream>>>(dWih0, wxD);

  // zero-init fp16 states (ping index 0)
  {
    int n4 = (int)(S16 / 16);
    zero_fill<<<(n4 + 255) / 256, 256, 0, stream>>>((float4*)h0h[0], n4);
    zero_fill<<<(n4 + 255) / 256, 256, 0, stream>>>((float4*)h1h[0], n4);
  }

  dim3 grid(2048), blk(256);
  int p0 = 0, p1 = 0;
  // encoder
  for (int t = 0; t < T_HIST; ++t) {
    gru_step<8, true><<<grid, blk, 0, stream>>>(pkE0, h0h[p0], nullptr,
                                                h0h[1 - p0], bE0, wxE,
                                                x_input + (size_t)t * 3, 150);
    p0 ^= 1;
    gru_step<16, false><<<grid, blk, 0, stream>>>(pkE1, h0h[p0], h1h[p1],
                                                  h1h[1 - p1], bE1, nullptr, nullptr, 0);
    p1 ^= 1;
  }
  // autoregressive decoder
  for (int t = 0; t < FUT; ++t) {
    const float* xp; int xs;
    if (t == 0) { xp = x_input + (size_t)49 * 3; xs = 150; }
    else        { xp = out + (size_t)(t - 1) * 3; xs = 90; }
    gru_step<8, true><<<grid, blk, 0, stream>>>(pkD0, h0h[p0], nullptr,
                                                h0h[1 - p0], bD0, wxD, xp, xs);
    p0 ^= 1;
    gru_step<16, false><<<grid, blk, 0, stream>>>(pkD1, h0h[p0], h1h[p1],
                                                  h1h[1 - p1], bD1, nullptr, nullptr, 0);
    p1 ^= 1;
    fc_kernel<<<8192, 256, 0, stream>>>(h1h[p1], fcW, fcb, out + (size_t)t * 3);
  }
}

// Round 7
// 15573.589 us; speedup vs baseline: 1.9824x; 1.1006x over previous
//
// TrajectoryPredictor: 2-layer GRU enc (50 steps) -> autoregressive 2-layer GRU dec (30 steps) + fc head.
// Strategy: fp16 MFMA (16x16x32_f16) GEMM per layer-step, gate math fused in epilogue; state fp16 ping-pong.
// R2: LDS granule swizzle -> conflicts 4.4e7 -> 0.
// R3/R5: XCD-aware block swizzle -> FETCH 278->145MB.
// R4/R5 lesson: acc regs count against unified per-wave budget; 128 acc + ~90 arch -> 2 waves/SIMD cap.
// R6 FAILED (core dump, unidentified; suspect the new 32x32 MFMA path) -> reverted to 16x16 code.
// R7: per-wave tile 32m x 32n (mt2 x nt2) -> 64 acc regs (~150 total <= 170) -> 3 waves/SIMD without
//     spill. Block 128m x 32n, 16 col-blocks, pack_w nb-width 32, LDS 28KB, grid 4096.
// ws ~137 MB: 4x fp16 state (128MB) + packed weights (9MB) + biases.
#include <hip/hip_runtime.h>
#include <hip/hip_fp16.h>
#include <stdint.h>

typedef _Float16 h8 __attribute__((ext_vector_type(8)));
typedef float f4 __attribute__((ext_vector_type(4)));

#define DEV static __device__ __forceinline__

constexpr int BATCH  = 32768;
constexpr int HID    = 512;
constexpr int T_HIST = 50;
constexpr int FUT    = 30;
constexpr int BM = 128, BN = 32, BK = 64;

DEV void gl2lds16(const void* g, void* l) {
  __builtin_amdgcn_global_load_lds(
      (const __attribute__((address_space(1))) void*)g,
      (__attribute__((address_space(3))) void*)l,
      16, 0, 0);
}

DEV float sigm(float x)     { return 1.f / (1.f + __expf(-x)); }
DEV float tanhfast(float x) { return 1.f - 2.f / (__expf(2.f * x) + 1.f); }

// ---------------- utility: zero fill (graph-safe) ----------------
__global__ void zero_fill(float4* __restrict__ p, int n4) {
  int i = blockIdx.x * 256 + threadIdx.x;
  if (i < n4) p[i] = float4{0.f, 0.f, 0.f, 0.f};
}

// ---------------- weight/bias repack kernels ----------------
// target layout: (((nb*KC + kc)*3 + g)*32 + n)*64 + k, 16 col-blocks of 32 n, with 16B-granule
// XOR swizzle: stored granule k8s holds logical k8 = k8s ^ (n&7). source row = g*512 + nb*32 + n.
__global__ void pack_w(const float* __restrict__ Wa, const float* __restrict__ Wb,
                       _Float16* __restrict__ out, int KC) {
  int i = blockIdx.x * 256 + threadIdx.x;
  int total = 16 * KC * 3 * 32 * 64;
  if (i >= total) return;
  int k0  = i & 7;          // element within 16B granule
  int k8s = (i >> 3) & 7;   // stored granule index
  int n   = (i >> 6) & 31;
  int t   = i >> 11;        // (nb*KC + kc)*3 + g
  int g   = t % 3;
  int t2  = t / 3;
  int kc  = t2 % KC;
  int nb  = t2 / KC;
  int k8  = k8s ^ (n & 7);  // logical granule
  int row = g * 512 + nb * 32 + n;
  int kg  = kc * 64 + k8 * 8 + k0;
  float v = (kg < 512) ? Wa[(size_t)row * 512 + kg] : Wb[(size_t)row * 512 + kg - 512];
  out[i] = (_Float16)v;
}

// bias combine: [0]=b_ih_r+b_hh_r, [1]=b_ih_z+b_hh_z, [2]=b_ih_n, [3]=b_hh_n  (each 512)
__global__ void pack_bias(const float* __restrict__ bih, const float* __restrict__ bhh,
                          float* __restrict__ out) {
  int j = blockIdx.x * 256 + threadIdx.x;
  if (j >= 512) return;
  out[j]        = bih[j]        + bhh[j];
  out[512 + j]  = bih[512 + j]  + bhh[512 + j];
  out[1024 + j] = bih[1024 + j];
  out[1536 + j] = bhh[1024 + j];
}

// x-weights for layer0 (K=3): out[j*9 + g*3 + k] = W_ih[(g*512+j)*3 + k]
__global__ void pack_wx(const float* __restrict__ Wih, float* __restrict__ out) {
  int i = blockIdx.x * 256 + threadIdx.x;
  if (i >= 512 * 9) return;
  int j = i / 9, q = i % 9, g = q / 3, k = q % 3;
  out[i] = Wih[(size_t)(g * 512 + j) * 3 + k];
}

// ---------------- fused GRU layer-step GEMM ----------------
// Block: 128m x 32n, 4 waves; wave w covers rows w*32..w*32+31, all 32 cols (mt2 x nt2, 64 acc regs).
// KC = Ktot/64 (8 for layer0, 16 for layer1). L0: x-part (K=3) handled in epilogue via Wx.
// Grid: flat 4096; XCD-aware remap (16 col-blocks of a row-block land on one XCD, adjacent in time).
template <int KC, bool L0>
__launch_bounds__(256, 3)
__global__ void gru_step(const _Float16* __restrict__ Bp,     // packed weights [16][KC][3][32][64] (swizzled)
                         const _Float16* __restrict__ Alo,    // fp16 A, k<512 (L0: old state; L1: layer0 out)
                         const _Float16* __restrict__ Ahi,    // fp16 A, k>=512 (L1: old state)
                         _Float16* __restrict__ hnew16,       // fp16 new state
                         const float* __restrict__ bias,      // [4*512]
                         const float* __restrict__ Wx,        // [512*9] (L0) or null
                         const float* __restrict__ xin,       // x row base (L0) or null
                         int xstride) {
  __shared__ alignas(16) _Float16 sA[BM * BK];        // [m][k] 16KB, granule-swizzled
  __shared__ alignas(16) _Float16 sB[3 * BN * BK];    // [g][n][k] 12KB, granule-swizzled

  const int tid  = threadIdx.x;
  const int wave = tid >> 6;
  const int lane = tid & 63;
  const int quad = lane >> 4;
  const int l15  = lane & 15;
  // XCD-aware swizzle: XCD ~ L mod 8. The 16 col-blocks of one row-block are spaced 8 in L:
  // same XCD, temporally adjacent -> A-tile L2-resident across its 16 stagings.
  const int L  = blockIdx.x;
  const int c  = L & 7;
  const int q  = L >> 3;                  // 0..511
  const int cb = q & 15;                  // 0..15
  const int rb = (c << 5) | (q >> 4);     // 0..255
  const int row0 = rb * BM;
  const int col0 = cb * BN;

  f4 acc_r[2][2]  = {};
  f4 acc_z[2][2]  = {};
  f4 acc_n0[2][2] = {};   // L1: i_n (kc<8); L0 unused
  f4 acc_n1[2][2] = {};   // h_n

  const _Float16* Bblk = Bp + (size_t)cb * KC * (3 * BN * BK);

  for (int kc = 0; kc < KC; ++kc) {
    const _Float16* Asrc = (KC == 16 && kc >= 8) ? Ahi : Alo;
    const int kb = (kc & 7) * BK;
    // stage A: 128x64 fp16, 4 issues/wave. LDS slot (m,k8s) holds logical granule k8s^(m&7);
    // lane fetches the permuted granule from global (dest is fixed wave-uniform base + lane*16).
#pragma unroll
    for (int i = 0; i < 4; ++i) {
      int ga = wave * 256 + i * 64 + lane;   // slot = m*8 + k8s
      int m = ga >> 3, k8s = ga & 7;
      int k8l = k8s ^ (m & 7);
      gl2lds16(Asrc + (size_t)(row0 + m) * HID + kb + k8l * 8,
               &sA[(wave * 256 + i * 64) * 8]);
    }
    // stage B: 12KB linear copy (swizzle pre-baked by pack_w), 3 issues/wave
    const _Float16* Bsrc = Bblk + (size_t)kc * (3 * BN * BK);
#pragma unroll
    for (int i = 0; i < 3; ++i) {
      int gb = wave * 192 + i * 64 + lane;
      gl2lds16(Bsrc + (size_t)gb * 8, &sB[(wave * 192 + i * 64) * 8]);
    }
    __syncthreads();   // drains vmcnt then barriers
#pragma unroll
    for (int s = 0; s < 2; ++s) {
      // swizzled granule offset (halfs): rows ≡ l15 (mod 8) for both A and B reads
      const int sw = ((s * 4 + quad) ^ (l15 & 7)) * 8;
      h8 af[2];
#pragma unroll
      for (int mt = 0; mt < 2; ++mt)
        af[mt] = *(const h8*)&sA[(wave * 32 + mt * 16 + l15) * BK + sw];
#pragma unroll
      for (int nt = 0; nt < 2; ++nt) {
        const int nrow = nt * 16 + l15;
        h8 br = *(const h8*)&sB[(0 * BN + nrow) * BK + sw];
        h8 bz = *(const h8*)&sB[(1 * BN + nrow) * BK + sw];
        h8 bn = *(const h8*)&sB[(2 * BN + nrow) * BK + sw];
#pragma unroll
        for (int mt = 0; mt < 2; ++mt) {
          acc_r[mt][nt] = __builtin_amdgcn_mfma_f32_16x16x32_f16(af[mt], br, acc_r[mt][nt], 0, 0, 0);
          acc_z[mt][nt] = __builtin_amdgcn_mfma_f32_16x16x32_f16(af[mt], bz, acc_z[mt][nt], 0, 0, 0);
          if (L0 || kc >= 8)
            acc_n1[mt][nt] = __builtin_amdgcn_mfma_f32_16x16x32_f16(af[mt], bn, acc_n1[mt][nt], 0, 0, 0);
          else
            acc_n0[mt][nt] = __builtin_amdgcn_mfma_f32_16x16x32_f16(af[mt], bn, acc_n0[mt][nt], 0, 0, 0);
        }
      }
    }
    __syncthreads();
  }

  // ---------------- fused epilogue: gates + state update ----------------
  const _Float16* hold16 = L0 ? Alo : Ahi;
  float bR[2], bZ[2], bI[2], bH[2];
  float wx[2][9];
#pragma unroll
  for (int nt = 0; nt < 2; ++nt) {
    int j = col0 + nt * 16 + l15;
    bR[nt] = bias[j];
    bZ[nt] = bias[512 + j];
    bI[nt] = bias[1024 + j];
    bH[nt] = bias[1536 + j];
    if constexpr (L0) {
#pragma unroll
      for (int q2 = 0; q2 < 9; ++q2) wx[nt][q2] = Wx[j * 9 + q2];
    }
  }
  float xv[2][4][3];
  if constexpr (L0) {
#pragma unroll
    for (int mt = 0; mt < 2; ++mt)
#pragma unroll
      for (int r = 0; r < 4; ++r) {
        int b = row0 + wave * 32 + mt * 16 + quad * 4 + r;
        const float* xp = xin + (size_t)b * xstride;
        xv[mt][r][0] = xp[0]; xv[mt][r][1] = xp[1]; xv[mt][r][2] = xp[2];
      }
  }
#pragma unroll
  for (int mt = 0; mt < 2; ++mt) {
#pragma unroll
    for (int r = 0; r < 4; ++r) {
      int b = row0 + wave * 32 + mt * 16 + quad * 4 + r;   // C/D: row = quad*4+reg
#pragma unroll
      for (int nt = 0; nt < 2; ++nt) {
        int j = col0 + nt * 16 + l15;                       // C/D: col = lane&15
        size_t idx = (size_t)b * HID + j;
        float rr = acc_r[mt][nt][r] + bR[nt];
        float zz = acc_z[mt][nt][r] + bZ[nt];
        float hn = acc_n1[mt][nt][r] + bH[nt];
        float in_;
        if constexpr (L0) {
          const float* w = wx[nt];
          rr += xv[mt][r][0] * w[0] + xv[mt][r][1] * w[1] + xv[mt][r][2] * w[2];
          zz += xv[mt][r][0] * w[3] + xv[mt][r][1] * w[4] + xv[mt][r][2] * w[5];
          in_ = bI[nt] + xv[mt][r][0] * w[6] + xv[mt][r][1] * w[7] + xv[mt][r][2] * w[8];
        } else {
          in_ = acc_n0[mt][nt][r] + bI[nt];
        }
        float rg = sigm(rr);
        float zg = sigm(zz);
        float ng = tanhfast(in_ + rg * hn);
        float hp = (float)hold16[idx];
        float hv = (1.f - zg) * ng + zg * hp;
        hnew16[idx] = (_Float16)hv;
      }
    }
  }
}

// ---------------- fc head: pred[b,d] = h[b,:] . fcW[d,:] + fcb[d] ----------------
__global__ __launch_bounds__(256) void fc_kernel(const _Float16* __restrict__ h,
                                                 const float* __restrict__ W,
                                                 const float* __restrict__ bfc,
                                                 float* __restrict__ out) {  // out = d_out + t*3
  int wave = threadIdx.x >> 6, lane = threadIdx.x & 63;
  int b = blockIdx.x * 4 + wave;
  const h8* hp = (const h8*)(h + (size_t)b * 512);
  h8 a0 = hp[lane];
  float s[3];
#pragma unroll
  for (int d = 0; d < 3; ++d) {
    const float4* wp = (const float4*)(W + d * 512);
    float4 w0 = wp[lane * 2], w1 = wp[lane * 2 + 1];
    s[d] = (float)a0[0] * w0.x + (float)a0[1] * w0.y + (float)a0[2] * w0.z + (float)a0[3] * w0.w
         + (float)a0[4] * w1.x + (float)a0[5] * w1.y + (float)a0[6] * w1.z + (float)a0[7] * w1.w;
  }
#pragma unroll
  for (int d = 0; d < 3; ++d)
#pragma unroll
    for (int off = 32; off > 0; off >>= 1) s[d] += __shfl_xor(s[d], off, 64);
  if (lane == 0) {
    out[(size_t)b * 90 + 0] = s[0] + bfc[0];
    out[(size_t)b * 90 + 1] = s[1] + bfc[1];
    out[(size_t)b * 90 + 2] = s[2] + bfc[2];
  }
}

extern "C" void kernel_launch(void* const* d_in, const int* in_sizes, int n_in,
                              void* d_out, int out_size, void* d_ws, size_t ws_size,
                              hipStream_t stream) {
  (void)in_sizes; (void)n_in; (void)out_size; (void)ws_size;
  const float* x_input = (const float*)d_in[0];
  const float* eWih0 = (const float*)d_in[2];
  const float* eWhh0 = (const float*)d_in[3];
  const float* ebih0 = (const float*)d_in[4];
  const float* ebhh0 = (const float*)d_in[5];
  const float* eWih1 = (const float*)d_in[6];
  const float* eWhh1 = (const float*)d_in[7];
  const float* ebih1 = (const float*)d_in[8];
  const float* ebhh1 = (const float*)d_in[9];
  const float* dWih0 = (const float*)d_in[10];
  const float* dWhh0 = (const float*)d_in[11];
  const float* dbih0 = (const float*)d_in[12];
  const float* dbhh0 = (const float*)d_in[13];
  const float* dWih1 = (const float*)d_in[14];
  const float* dWhh1 = (const float*)d_in[15];
  const float* dbih1 = (const float*)d_in[16];
  const float* dbhh1 = (const float*)d_in[17];
  const float* fcW   = (const float*)d_in[18];
  const float* fcb   = (const float*)d_in[19];
  float* out = (float*)d_out;

  char* ws = (char*)d_ws;
  const size_t S16 = (size_t)BATCH * HID * 2;   // 32MB
  _Float16* h0h[2] = {(_Float16*)(ws),            (_Float16*)(ws + S16)};
  _Float16* h1h[2] = {(_Float16*)(ws + 2 * S16),  (_Float16*)(ws + 3 * S16)};
  char* p = ws + 4 * S16;                        // 128MB
  const size_t W8  = (size_t)16 * 8  * 3 * 32 * 64 * 2;  // 1.5MB (KC=8)
  const size_t W16 = (size_t)16 * 16 * 3 * 32 * 64 * 2;  // 3MB (KC=16)
  _Float16* pkE0 = (_Float16*)p; p += W8;
  _Float16* pkE1 = (_Float16*)p; p += W16;
  _Float16* pkD0 = (_Float16*)p; p += W8;
  _Float16* pkD1 = (_Float16*)p; p += W16;
  float* bE0 = (float*)p; p += 2048 * 4;
  float* bE1 = (float*)p; p += 2048 * 4;
  float* bD0 = (float*)p; p += 2048 * 4;
  float* bD1 = (float*)p; p += 2048 * 4;
  float* wxE = (float*)p; p += 512 * 9 * 4;
  float* wxD = (float*)p; p += 512 * 9 * 4;
  // total ws usage: 128MB + ~9.1MB

  // repack weights/biases (every call; ws is re-poisoned by harness)
  pack_w<<<dim3(3072), 256, 0, stream>>>(eWhh0, eWhh0, pkE0, 8);
  pack_w<<<dim3(6144), 256, 0, stream>>>(eWih1, eWhh1, pkE1, 16);
  pack_w<<<dim3(3072), 256, 0, stream>>>(dWhh0, dWhh0, pkD0, 8);
  pack_w<<<dim3(6144), 256, 0, stream>>>(dWih1, dWhh1, pkD1, 16);
  pack_bias<<<2, 256, 0, stream>>>(ebih0, ebhh0, bE0);
  pack_bias<<<2, 256, 0, stream>>>(ebih1, ebhh1, bE1);
  pack_bias<<<2, 256, 0, stream>>>(dbih0, dbhh0, bD0);
  pack_bias<<<2, 256, 0, stream>>>(dbih1, dbhh1, bD1);
  pack_wx<<<18, 256, 0, stream>>>(eWih0, wxE);
  pack_wx<<<18, 256, 0, stream>>>(dWih0, wxD);

  // zero-init fp16 states (ping index 0)
  {
    int n4 = (int)(S16 / 16);
    zero_fill<<<(n4 + 255) / 256, 256, 0, stream>>>((float4*)h0h[0], n4);
    zero_fill<<<(n4 + 255) / 256, 256, 0, stream>>>((float4*)h1h[0], n4);
  }

  dim3 grid(4096), blk(256);
  int p0 = 0, p1 = 0;
  // encoder
  for (int t = 0; t < T_HIST; ++t) {
    gru_step<8, true><<<grid, blk, 0, stream>>>(pkE0, h0h[p0], nullptr,
                                                h0h[1 - p0], bE0, wxE,
                                                x_input + (size_t)t * 3, 150);
    p0 ^= 1;
    gru_step<16, false><<<grid, blk, 0, stream>>>(pkE1, h0h[p0], h1h[p1],
                                                  h1h[1 - p1], bE1, nullptr, nullptr, 0);
    p1 ^= 1;
  }
  // autoregressive decoder
  for (int t = 0; t < FUT; ++t) {
    const float* xp; int xs;
    if (t == 0) { xp = x_input + (size_t)49 * 3; xs = 150; }
    else        { xp = out + (size_t)(t - 1) * 3; xs = 90; }
    gru_step<8, true><<<grid, blk, 0, stream>>>(pkD0, h0h[p0], nullptr,
                                                h0h[1 - p0], bD0, wxD, xp, xs);
    p0 ^= 1;
    gru_step<16, false><<<grid, blk, 0, stream>>>(pkD1, h0h[p0], h1h[p1],
                                                  h1h[1 - p1], bD1, nullptr, nullptr, 0);
    p1 ^= 1;
    fc_kernel<<<8192, 256, 0, stream>>>(h1h[p1], fcW, fcb, out + (size_t)t * 3);
  }
}